// Round 4
// baseline (950.709 us; speedup 1.0000x reference)
//
#include <hip/hip_runtime.h>

#define N_NODES 50000
#define N_PAD   50048          // 391 * 128
#define N_EDGES 800000
#define N_REL   8
#define NSEG    (N_REL * N_NODES)      // 400000
#define SCAN_NB 391                    // ceil(NSEG / 1024)

typedef short bf16x8 __attribute__((ext_vector_type(8)));
typedef float f32x4  __attribute__((ext_vector_type(4)));

__device__ __forceinline__ ushort f2bf(float f) {
    union { float f; unsigned u; } c; c.f = f;
    unsigned u = c.u + 0x7fffu + ((c.u >> 16) & 1u);   // RNE
    return (ushort)(u >> 16);
}
__device__ __forceinline__ void add8(float* s, uint4 v) {
    unsigned u[4] = {v.x, v.y, v.z, v.w};
    #pragma unroll
    for (int k = 0; k < 4; ++k) {
        s[2 * k]     += __uint_as_float(u[k] << 16);
        s[2 * k + 1] += __uint_as_float(u[k] & 0xffff0000u);
    }
}
__device__ __forceinline__ void async16(const ushort* g, ushort* l) {
    __builtin_amdgcn_global_load_lds((const __attribute__((address_space(1))) void*)g,
                                     (__attribute__((address_space(3))) void*)l, 16, 0, 0);
}

// ---------------- edge preprocessing: counting sort by (rel*N + dst) ----------------

__global__ void count_edges(const int* __restrict__ dst, const int* __restrict__ et,
                            int* __restrict__ cnt) {
    int e = blockIdx.x * 256 + threadIdx.x;
    if (e < N_EDGES) atomicAdd(&cnt[et[e] * N_NODES + dst[e]], 1);
}

__global__ __launch_bounds__(256) void scan_pass1(const int* __restrict__ cnt,
                                                  int* __restrict__ sums) {
    __shared__ int sc[256];
    int b = blockIdx.x, t = threadIdx.x;
    int base = b * 1024 + t * 4;
    int v = 0;
    #pragma unroll
    for (int i = 0; i < 4; ++i) { int idx = base + i; if (idx < NSEG) v += cnt[idx]; }
    sc[t] = v; __syncthreads();
    for (int off = 1; off < 256; off <<= 1) {
        int x = (t >= off) ? sc[t - off] : 0;
        __syncthreads(); sc[t] += x; __syncthreads();
    }
    if (t == 255) sums[b] = sc[255];
}

__global__ __launch_bounds__(512) void scan_pass2(int* __restrict__ sums, int nb) {
    __shared__ int sc[512];
    int t = threadIdx.x;
    int v = (t < nb) ? sums[t] : 0;
    sc[t] = v; __syncthreads();
    for (int off = 1; off < 512; off <<= 1) {
        int x = (t >= off) ? sc[t - off] : 0;
        __syncthreads(); sc[t] += x; __syncthreads();
    }
    if (t < nb) sums[t] = sc[t] - v;     // exclusive
}

__global__ __launch_bounds__(256) void scan_pass3(const int* __restrict__ cnt,
                                                  const int* __restrict__ sums,
                                                  int* __restrict__ row_ptr) {
    __shared__ int sc[256];
    int b = blockIdx.x, t = threadIdx.x;
    int base = b * 1024 + t * 4;
    int e[4]; int v = 0;
    #pragma unroll
    for (int i = 0; i < 4; ++i) { int idx = base + i; e[i] = (idx < NSEG) ? cnt[idx] : 0; v += e[i]; }
    sc[t] = v; __syncthreads();
    for (int off = 1; off < 256; off <<= 1) {
        int x = (t >= off) ? sc[t - off] : 0;
        __syncthreads(); sc[t] += x; __syncthreads();
    }
    int run = sums[b] + (sc[t] - v);
    #pragma unroll
    for (int i = 0; i < 4; ++i) {
        int idx = base + i;
        if (idx < NSEG) row_ptr[idx] = run;
        run += e[i];
    }
    if (b == 0 && t == 0) row_ptr[NSEG] = N_EDGES;
}

// cnt doubles as the placement cursor (atomicSub); cnt is dead afterwards.
__global__ void place_edges(const int* __restrict__ src, const int* __restrict__ dst,
                            const int* __restrict__ et, const int* __restrict__ row_ptr,
                            int* __restrict__ cnt, int* __restrict__ sorted_src) {
    int e = blockIdx.x * 256 + threadIdx.x;
    if (e >= N_EDGES) return;
    int key = et[e] * N_NODES + dst[e];
    int old = atomicSub(&cnt[key], 1);
    sorted_src[row_ptr[key] + old - 1] = src[e];
}

// ---------------- weight pack: BT[col][kk], kk = r*K+i -> W[r][i][col], r=8 -> root ----------------

__global__ void convert_weights(const float* __restrict__ W, const float* __restrict__ root,
                                ushort* __restrict__ BT, int K, int O, int NBT) {
    int KT = 9 * K;
    int idx = blockIdx.x * 256 + threadIdx.x;
    if (idx >= NBT * KT) return;
    int col = idx / KT, kk = idx % KT;
    float v = 0.0f;
    if (col < O) {
        int r = kk / K, i = kk % K;
        v = (r < N_REL) ? W[((size_t)r * K + i) * O + col] : root[(size_t)i * O + col];
    }
    BT[idx] = f2bf(v);
}

__global__ void f32_to_bf16(const float* __restrict__ in, ushort* __restrict__ out, int n4) {
    int i = blockIdx.x * 256 + threadIdx.x;
    if (i >= n4) return;
    float4 v = ((const float4*)in)[i];
    ushort4 s; s.x = f2bf(v.x); s.y = f2bf(v.y); s.z = f2bf(v.z); s.w = f2bf(v.w);
    ((ushort4*)out)[i] = s;
}

// ---------------- segment mean into wide-A layout: Agg[d][r*K + c] ----------------
// Thread owns (dst, rel, 8-col chunk); rel==8 is the identity copy of h (root operand).
// h is ~25 MB -> L2/L3-resident; random per-edge reads are cache hits, writes are
// contiguous full lines (no write-allocate).
template<int K>
__global__ __launch_bounds__(256)
void segsum_kernel(const ushort* __restrict__ h, const int* __restrict__ row_ptr,
                   const int* __restrict__ sorted_src, ushort* __restrict__ Agg) {
    constexpr int TPN = K / 8;               // threads per (d, r): 16 or 32
    constexpr int DPB = 256 / TPN;           // dst nodes per block
    const int KT = 9 * K;
    int d = blockIdx.x * DPB + (int)threadIdx.x / TPN;
    int r = blockIdx.y;                      // 0..8
    int c0 = ((int)threadIdx.x % TPN) * 8;
    if (d >= N_NODES) return;
    ushort* outp = Agg + (size_t)d * KT + r * K + c0;
    if (r == N_REL) {                        // identity: Agg[d][8K+c] = h[d][c]
        *(uint4*)outp = *(const uint4*)(h + (size_t)d * K + c0);
        return;
    }
    int base = r * N_NODES + d;
    int s0 = row_ptr[base], s1 = row_ptr[base + 1];
    float sum[8] = {};
    for (int e = s0; e < s1; ++e)
        add8(sum, *(const uint4*)(h + (size_t)sorted_src[e] * K + c0));
    float inv = (s1 > s0) ? 1.0f / (float)(s1 - s0) : 0.0f;
    ushort o[8];
    #pragma unroll
    for (int k = 0; k < 8; ++k) o[k] = f2bf(sum[k] * inv);
    *(uint4*)outp = *(const uint4*)o;
}

// ---------------- bf16 MFMA GEMM (m97 structure): C = Agg[N_PAD,KT] @ BT[NBT,KT]^T ----------------
// Epilogue fuses bias + ReLU; writes bf16 h (all rows) or fp32 d_out (guarded rows/cols).
__global__ __launch_bounds__(256)
void gemm_mfma(const ushort* __restrict__ A, const ushort* __restrict__ BT,
               const float* __restrict__ bias, int KT, int O, int relu,
               ushort* __restrict__ Cb, float* __restrict__ Cf) {
    __shared__ ushort As[128 * 32];   // 8 KB, 64B rows, no padding (global_load_lds layout)
    __shared__ ushort Bs[128 * 32];
    const int t = threadIdx.x;
    const int lane = t & 63;
    const int w = t >> 6;
    const int l16 = lane & 15, q = lane >> 4;
    const int wm = (w & 1) * 64, wn = (w >> 1) * 64;
    const int col0 = blockIdx.x * 128;   // x = column block: adjacent blocks share A-tiles in L2/L3
    const int row0 = blockIdx.y * 128;

    // staging: chunk ci (0..255) covers rows 0..63; +64*KT covers rows 64..127.
    // LDS dst = wave-uniform base + lane*16 (required by global_load_lds).
    const int ci = w * 64 + lane;
    const size_t ga0 = (size_t)(ci >> 2) * KT + (size_t)((ci & 3) << 3);
    const ushort* Ab = A + (size_t)row0 * KT;
    const ushort* Bb = BT + (size_t)col0 * KT;
    const size_t half = (size_t)64 * KT;
    ushort* lA0 = &As[w * 512];
    ushort* lA1 = &As[(w + 4) * 512];
    ushort* lB0 = &Bs[w * 512];
    ushort* lB1 = &Bs[(w + 4) * 512];

    f32x4 acc[4][4] = {};

    for (int k0 = 0; k0 < KT; k0 += 32) {
        __syncthreads();                       // previous iter's LDS reads done
        async16(Ab + ga0 + k0, lA0);
        async16(Ab + ga0 + half + k0, lA1);
        async16(Bb + ga0 + k0, lB0);
        async16(Bb + ga0 + half + k0, lB1);
        __syncthreads();                       // drains global_load_lds (vmcnt 0)
        bf16x8 a[4], b[4];
        #pragma unroll
        for (int i = 0; i < 4; ++i) {
            a[i] = *(const bf16x8*)&As[(wm + i * 16 + l16) * 32 + q * 8];
            b[i] = *(const bf16x8*)&Bs[(wn + i * 16 + l16) * 32 + q * 8];
        }
        #pragma unroll
        for (int i = 0; i < 4; ++i)
            #pragma unroll
            for (int j = 0; j < 4; ++j)
                acc[i][j] = __builtin_amdgcn_mfma_f32_16x16x32_bf16(a[i], b[j], acc[i][j], 0, 0, 0);
    }

    // epilogue: D mapping col=l16, row=q*4+reg (verified gfx950 layout)
    #pragma unroll
    for (int i = 0; i < 4; ++i) {
        int grow = row0 + wm + i * 16 + q * 4;
        #pragma unroll
        for (int j = 0; j < 4; ++j) {
            int gcol = col0 + wn + j * 16 + l16;
            if (gcol >= O) continue;           // layer 4: tile wider than O=64
            float bv = bias[gcol];
            #pragma unroll
            for (int r = 0; r < 4; ++r) {
                float v = acc[i][j][r] + bv;
                if (relu) v = fmaxf(v, 0.0f);
                int row = grow + r;
                if (Cb) Cb[(size_t)row * O + gcol] = f2bf(v);
                else if (row < N_NODES) Cf[(size_t)row * O + gcol] = v;
            }
        }
    }
}

// ---------------- host side ----------------

extern "C" void kernel_launch(void* const* d_in, const int* in_sizes, int n_in,
                              void* d_out, int out_size, void* d_ws, size_t ws_size,
                              hipStream_t stream) {
    const float* x  = (const float*)d_in[0];
    const int*   ei = (const int*)d_in[1];
    const int*   et = (const int*)d_in[2];
    const float* W[4]  = {(const float*)d_in[3], (const float*)d_in[6], (const float*)d_in[9],  (const float*)d_in[12]};
    const float* RT[4] = {(const float*)d_in[4], (const float*)d_in[7], (const float*)d_in[10], (const float*)d_in[13]};
    const float* BI[4] = {(const float*)d_in[5], (const float*)d_in[8], (const float*)d_in[11], (const float*)d_in[14]};
    const int KS[4]  = {128, 256, 256, 256};
    const int OS[4]  = {256, 256, 256, 64};
    const int NBT[4] = {256, 256, 256, 128};   // packed BT rows (>= O, tile multiple)
    const int* src = ei;
    const int* dst = ei + N_EDGES;

    // ---- workspace carve-up (~266 MB; round-3 plan A proved ws_size >= ~267 MB) ----
    char* ws = (char*)d_ws;
    size_t off = 0;
    auto take = [&](size_t bytes) -> char* {
        char* p = ws + off;
        off = (off + bytes + 255) & ~(size_t)255;
        return p;
    };
    int* cnt        = (int*)take((size_t)NSEG * 4);
    int* row_ptr    = (int*)take((size_t)(NSEG + 1) * 4);
    int* sums       = (int*)take(512 * 4);
    int* sorted_src = (int*)take((size_t)N_EDGES * 4);
    ushort* BTp[4];
    for (int l = 0; l < 4; ++l) BTp[l] = (ushort*)take((size_t)NBT[l] * 9 * KS[l] * 2);
    ushort* hb  = (ushort*)take((size_t)N_PAD * 256 * 2);   // layer activations, bf16
    ushort* Agg = (ushort*)take((size_t)N_PAD * 2304 * 2);  // wide GEMM A operand

    // ---- edge preprocessing (once per call) ----
    hipMemsetAsync(cnt, 0, (size_t)NSEG * 4, stream);
    count_edges<<<(N_EDGES + 255) / 256, 256, 0, stream>>>(dst, et, cnt);
    scan_pass1<<<SCAN_NB, 256, 0, stream>>>(cnt, sums);
    scan_pass2<<<1, 512, 0, stream>>>(sums, SCAN_NB);
    scan_pass3<<<SCAN_NB, 256, 0, stream>>>(cnt, sums, row_ptr);
    place_edges<<<(N_EDGES + 255) / 256, 256, 0, stream>>>(src, dst, et, row_ptr, cnt, sorted_src);

    // ---- weight pack ----
    for (int l = 0; l < 4; ++l) {
        int n = NBT[l] * 9 * KS[l];
        convert_weights<<<(n + 255) / 256, 256, 0, stream>>>(W[l], RT[l], BTp[l], KS[l], OS[l], NBT[l]);
    }

    // ---- input to bf16 ----
    f32_to_bf16<<<(N_NODES * 128 / 4 + 255) / 256, 256, 0, stream>>>(x, hb, N_NODES * 128 / 4);

    // ---- 4 layers: segsum (aggregate in feature space) + one wide-K GEMM ----
    for (int l = 0; l < 4; ++l) {
        const int K = KS[l], O = OS[l], KT = 9 * K;
        const bool last = (l == 3);
        if (K == 128)
            segsum_kernel<128><<<dim3((N_NODES + 15) / 16, 9), 256, 0, stream>>>(hb, row_ptr, sorted_src, Agg);
        else
            segsum_kernel<256><<<dim3((N_NODES + 7) / 8, 9), 256, 0, stream>>>(hb, row_ptr, sorted_src, Agg);
        gemm_mfma<<<dim3(NBT[l] / 128, N_PAD / 128), 256, 0, stream>>>(
            Agg, BTp[l], BI[l], KT, O, last ? 0 : 1,
            last ? nullptr : hb, last ? (float*)d_out : nullptr);
    }
}